// Round 3
// baseline (280.267 us; speedup 1.0000x reference)
//
#include <hip/hip_runtime.h>
#include <hip/hip_fp16.h>

#define CCH 64      // channels
#define RPB 32      // rows per bucket
#define PCH 8192    // edges per partition block
#define NBMAX 1568  // >= NB = ceil(50000/32) = 1563
#define GR 64       // rows per gemm block
#define SG 8        // buckets per sort block
#define STCAP 8192  // sort32 LDS staging capacity (recs)

typedef int int4a __attribute__((ext_vector_type(4), aligned(4)));

// ---- pass A: per-block bucket histogram -> H[c][blk][b] (no global atomics) ----
__global__ void __launch_bounds__(256) k_hist(const int* __restrict__ e0,
        const int* __restrict__ e1, const int* __restrict__ e2,
        int* __restrict__ H, int E, int NB, int NBLK) {
    int c = blockIdx.y;
    const int* dd = ((c == 0) ? e0 : (c == 1) ? e1 : e2) + E;
    int base = blockIdx.x * PCH;
    int nE = E - base; if (nE > PCH) nE = PCH;
    __shared__ int hist[NBMAX];
    int t = threadIdx.x;
    for (int i = t; i < NB; i += 256) hist[i] = 0;
    __syncthreads();
    for (int k = t * 4; k < nE; k += 1024) {
        if (k + 3 < nE) {
            int4a d = *(const int4a*)(dd + base + k);
            atomicAdd(&hist[d.x >> 5], 1); atomicAdd(&hist[d.y >> 5], 1);
            atomicAdd(&hist[d.z >> 5], 1); atomicAdd(&hist[d.w >> 5], 1);
        } else {
            for (int j = k; j < nE; ++j) atomicAdd(&hist[dd[base + j] >> 5], 1);
        }
    }
    __syncthreads();
    int* Hrow = H + ((size_t)c * NBLK + blockIdx.x) * NB;
    for (int i = t; i < NB; i += 256) Hrow[i] = hist[i];
}

// ---- bucket totals by summing H columns, then exclusive scan -> bstart.
//      Also zeroes zrow (kills two memset launches + hist atomics). ----
__global__ void __launch_bounds__(1024) k_bscan(const int* __restrict__ H,
        int* __restrict__ bstart, __half* __restrict__ zrow,
        int NB, int E, int NBLK) {
    int c = blockIdx.x, t = threadIdx.x;
    if (c == 0 && t < 32) ((float*)zrow)[t] = 0.f;
    __shared__ int sm[1024];
    int i0 = 2 * t, i1 = 2 * t + 1;
    const int* Hc = H + (size_t)c * NBLK * NB;
    int v0 = 0, v1 = 0;
    for (int blk = 0; blk < NBLK; ++blk) {
        const int* r = Hc + (size_t)blk * NB;
        if (i0 < NB) v0 += r[i0];
        if (i1 < NB) v1 += r[i1];
    }
    sm[t] = v0 + v1;
    __syncthreads();
    #pragma unroll
    for (int off = 1; off < 1024; off <<= 1) {
        int u = (t >= off) ? sm[t - off] : 0;
        __syncthreads();
        sm[t] += u;
        __syncthreads();
    }
    int ex = sm[t] - (v0 + v1);
    if (i0 < NB) bstart[c * (NB + 1) + i0] = ex;
    if (i1 < NB) bstart[c * (NB + 1) + i1] = ex + v0;
    if (t == 0) bstart[c * (NB + 1) + NB] = E;
}

// ---- pass B: per-bucket scan over blocks: H <- bstart + prefix ----
__global__ void __launch_bounds__(256) k_colscan(int* __restrict__ H,
        const int* __restrict__ bstart, int NB, int NBLK) {
    int c = blockIdx.y;
    int b = blockIdx.x * 4 + (threadIdx.x >> 6);
    if (b >= NB) return;
    int l = threadIdx.x & 63;
    int* Hc = H + (size_t)c * NBLK * NB;
    int run = bstart[c * (NB + 1) + b];
    for (int c0 = 0; c0 < NBLK; c0 += 64) {
        int blk = c0 + l;
        int v = (blk < NBLK) ? Hc[(size_t)blk * NB + b] : 0;
        int s = v;
        #pragma unroll
        for (int off = 1; off < 64; off <<= 1) {
            int u = __shfl_up(s, off, 64);
            if (l >= off) s += u;
        }
        if (blk < NBLK) Hc[(size_t)blk * NB + b] = run + s - v;
        run += __shfl(s, 63, 64);
    }
}

// ---- pass C: LDS-STAGED partition. Local counts via the H-diff identity
//      h_local[blk][b] = H[blk+1][b] - H[blk][b] (bstart[b+1] for last block):
//      no edge re-read, no histogram atomics (verified R1). ----
__global__ void __launch_bounds__(256) k_part2(const int* __restrict__ e0,
        const int* __restrict__ e1, const int* __restrict__ e2,
        const int* __restrict__ H, const int* __restrict__ bstart,
        unsigned* __restrict__ bdata, int E, int NB, int NBLK) {
    int c = blockIdx.y;
    const int* ed = (c == 0) ? e0 : (c == 1) ? e1 : e2;
    int base = blockIdx.x * PCH;
    int nE = E - base; if (nE > PCH) nE = PCH;
    __shared__ unsigned staged[PCH];    // 32 KB
    __shared__ int hist[NBMAX];
    __shared__ int off[NBMAX];
    __shared__ int sm[256];
    int t = threadIdx.x;
    const int* Hcur = H + ((size_t)c * NBLK + blockIdx.x) * NB;
    const int* Hnxt = (blockIdx.x == NBLK - 1) ? (bstart + c * (NB + 1) + 1)
                                               : (Hcur + NB);
    for (int i = t; i < NB; i += 256) {
        int cu = Hcur[i];
        off[i] = cu;
        hist[i] = Hnxt[i] - cu;         // this block's local count for bucket i
    }
    __syncthreads();
    int C = (NB + 255) >> 8;
    int lo = t * C, hi = lo + C; if (hi > NB) hi = NB; if (lo > NB) lo = NB;
    int s = 0;
    for (int i = lo; i < hi; ++i) s += hist[i];
    sm[t] = s;
    __syncthreads();
    #pragma unroll
    for (int o = 1; o < 256; o <<= 1) {
        int u = (t >= o) ? sm[t - o] : 0;
        __syncthreads();
        sm[t] += u;
        __syncthreads();
    }
    int run = (t == 0) ? 0 : sm[t - 1];
    for (int i = lo; i < hi; ++i) {
        int h = hist[i];
        off[i] -= run;      // global offset minus staging start
        hist[i] = run;      // staging cursor
        run += h;
    }
    __syncthreads();
    for (int k = t * 4; k < nE; k += 1024) {
        if (k + 3 < nE) {
            int4a s4 = *(const int4a*)(ed + base + k);
            int4a d4 = *(const int4a*)(ed + E + base + k);
            int sl;
            sl = atomicAdd(&hist[d4.x >> 5], 1); staged[sl] = (unsigned)s4.x | ((unsigned)d4.x << 16);
            sl = atomicAdd(&hist[d4.y >> 5], 1); staged[sl] = (unsigned)s4.y | ((unsigned)d4.y << 16);
            sl = atomicAdd(&hist[d4.z >> 5], 1); staged[sl] = (unsigned)s4.z | ((unsigned)d4.z << 16);
            sl = atomicAdd(&hist[d4.w >> 5], 1); staged[sl] = (unsigned)s4.w | ((unsigned)d4.w << 16);
        } else {
            for (int j = k; j < nE; ++j) {
                int s0 = ed[base + j];
                int d0 = ed[E + base + j];
                int sl = atomicAdd(&hist[d0 >> 5], 1);
                staged[sl] = (unsigned)s0 | ((unsigned)d0 << 16);
            }
        }
    }
    __syncthreads();
    unsigned* bo = bdata + (size_t)c * E;
    for (int sI = t; sI < nE; sI += 256) {
        unsigned rec = staged[sI];
        int b = (int)(rec >> 16) >> 5;
        bo[off[b] + sI] = rec;
    }
}

// ---- within-bucket 32-way counting sort, SG buckets per block,
//      SINGLE global read: recs staged in LDS (fallback if region > STCAP) ----
__global__ void __launch_bounds__(256) k_sort32(const unsigned* __restrict__ bdata,
        const int* __restrict__ bstart, int* __restrict__ sdat,
        int* __restrict__ rs, float* __restrict__ dinv, int E, int N, int NB) {
    int c = blockIdx.y;
    int b0 = blockIdx.x * SG;
    __shared__ unsigned staged[STCAP];  // 32 KB
    __shared__ int cnt[SG * RPB];
    __shared__ int cur[SG * RPB];
    __shared__ int sb[SG + 1];
    int t = threadIdx.x;
    cnt[t] = 0;
    if (t <= SG) {
        int b = b0 + t; if (b > NB) b = NB;
        sb[t] = bstart[c * (NB + 1) + b];
    }
    __syncthreads();
    int s0 = sb[0], sE = sb[SG];
    int n = sE - s0;
    const unsigned* bd = bdata + (size_t)c * E;
    bool fits = (n <= STCAP);
    if (fits) {
        for (int i = t; i < n; i += 256) staged[i] = bd[s0 + i];
        __syncthreads();
        for (int i = t; i < n; i += 256) {
            int dst = (int)(staged[i] >> 16);
            atomicAdd(&cnt[((dst >> 5) - b0) * RPB + (dst & 31)], 1);
        }
    } else {
        for (int i = s0 + t; i < sE; i += 256) {
            int dst = (int)(bd[i] >> 16);
            atomicAdd(&cnt[((dst >> 5) - b0) * RPB + (dst & 31)], 1);
        }
    }
    __syncthreads();
    {
        int v = cnt[t];
        int s = v;
        #pragma unroll
        for (int off = 1; off < RPB; off <<= 1) {
            int u = __shfl_up(s, off, RPB);
            if ((t & (RPB - 1)) >= off) s += u;
        }
        int g = t >> 5, r = t & 31;
        int ex = sb[g] + s - v;
        cur[t] = ex;
        int row = (b0 + g) * RPB + r;
        if (b0 + g < NB && row < N) {
            rs[c * (N + 1) + row] = ex;
            dinv[c * N + row] = rsqrtf((float)(v + 1));
        }
    }
    if (blockIdx.x == 0 && t == 0) rs[c * (N + 1) + N] = E;
    __syncthreads();
    int* so = sdat + (size_t)c * E;
    if (fits) {
        for (int i = t; i < n; i += 256) {
            unsigned r = staged[i];
            int dst = (int)(r >> 16);
            int slot = atomicAdd(&cur[((dst >> 5) - b0) * RPB + (dst & 31)], 1);
            so[slot] = (int)(r & 0xFFFFu);
        }
    } else {
        for (int i = s0 + t; i < sE; i += 256) {
            unsigned r = bd[i];
            int dst = (int)(r >> 16);
            int slot = atomicAdd(&cur[((dst >> 5) - b0) * RPB + (dst & 31)], 1);
            so[slot] = (int)(r & 0xFFFFu);
        }
    }
}

// ---- h16[c,row,:] = fp16( (x_row . W_c) * dinv[c,row] ), register-tiled ----
__global__ void __launch_bounds__(256) k_gemm_all(const float* __restrict__ xs_,
        const float* __restrict__ xg_, const float* __restrict__ W0,
        const float* __restrict__ W1, const float* __restrict__ W2,
        const float* __restrict__ dinv, __half* __restrict__ h16, int N) {
    int c = blockIdx.y;
    const float* x = (c == 2) ? xg_ : xs_;
    const float* W = (c == 0) ? W0 : (c == 1) ? W1 : W2;
    __shared__ float Ws[CCH * CCH];       // [k][col]
    __shared__ float xT[CCH * (GR + 1)];  // [k][row], stride 65
    int t = threadIdx.x;
    int row0 = blockIdx.x * GR;
    #pragma unroll
    for (int j = 0; j < 4; ++j) {
        int idx = j * 1024 + t * 4;
        *(float4*)(Ws + idx) = *(const float4*)(W + idx);
    }
    #pragma unroll
    for (int j = 0; j < 4; ++j) {
        int idx = t + j * 256;
        int r = idx >> 4;
        int c0 = (idx & 15) * 4;
        int row = row0 + r;
        float4 v = make_float4(0.f, 0.f, 0.f, 0.f);
        if (row < N) v = *(const float4*)(x + (size_t)row * CCH + c0);
        xT[(c0 + 0) * (GR + 1) + r] = v.x;
        xT[(c0 + 1) * (GR + 1) + r] = v.y;
        xT[(c0 + 2) * (GR + 1) + r] = v.z;
        xT[(c0 + 3) * (GR + 1) + r] = v.w;
    }
    __syncthreads();
    int c4 = (t & 15) * 4;
    int r0 = (t >> 4) * 4;
    float4 a0 = make_float4(0.f, 0.f, 0.f, 0.f), a1 = a0, a2 = a0, a3 = a0;
    #pragma unroll 8
    for (int k = 0; k < CCH; ++k) {
        float4 wv = *(float4*)(Ws + k * CCH + c4);
        float x0 = xT[k * (GR + 1) + r0 + 0];
        float x1 = xT[k * (GR + 1) + r0 + 1];
        float x2 = xT[k * (GR + 1) + r0 + 2];
        float x3 = xT[k * (GR + 1) + r0 + 3];
        a0.x += x0 * wv.x; a0.y += x0 * wv.y; a0.z += x0 * wv.z; a0.w += x0 * wv.w;
        a1.x += x1 * wv.x; a1.y += x1 * wv.y; a1.z += x1 * wv.z; a1.w += x1 * wv.w;
        a2.x += x2 * wv.x; a2.y += x2 * wv.y; a2.z += x2 * wv.z; a2.w += x2 * wv.w;
        a3.x += x3 * wv.x; a3.y += x3 * wv.y; a3.z += x3 * wv.z; a3.w += x3 * wv.w;
    }
    const float* dv = dinv + c * N;
    __half* hc = h16 + (size_t)c * N * CCH;
    float4 av[4] = {a0, a1, a2, a3};
    #pragma unroll
    for (int i = 0; i < 4; ++i) {
        int row = row0 + r0 + i;
        if (row < N) {
            float dd = dv[row];
            union { __half2 h2[2]; float2 f2; } u;
            u.h2[0] = __floats2half2_rn(av[i].x * dd, av[i].y * dd);
            u.h2[1] = __floats2half2_rn(av[i].z * dd, av[i].w * dd);
            *(float2*)(hc + (size_t)row * CCH + c4) = u.f2;
        }
    }
}

// ---- gather 4 fp16 channels (8B dwordx2) from a row pointer ----
__device__ __forceinline__ float4 gat4p(const __half* __restrict__ p, int l16) {
    union { float2 f2; __half2 h2[2]; } u;
    u.f2 = ((const float2*)p)[l16];
    float2 a = __half22float2(u.h2[0]);
    float2 b = __half22float2(u.h2[1]);
    return make_float4(a.x, a.y, b.x, b.y);
}

__device__ __forceinline__ void acc4(float4& a, float4 v) {
    a.x += v.x; a.y += v.y; a.z += v.z; a.w += v.w;
}

// ---- fused pull: wave per row; four quarter-waves (16 lanes x 4ch) walk
//      4 list segments. Main loop = R0's unpredicated 8-wide (VALU-lean);
//      tail = ONE masked 8-wide shot via L1-hot zero row (kills the serial
//      scalar chain without R2's per-iteration cndmask tax). ----
__global__ void __launch_bounds__(256) k_pull(const int* __restrict__ rs,
        const int* __restrict__ sdat, const __half* __restrict__ h16,
        const float* __restrict__ dinv, const __half* __restrict__ zrow,
        const float* __restrict__ b0, const float* __restrict__ b1,
        const float* __restrict__ b2,
        float* __restrict__ out, int N, int E) {
    int row = blockIdx.x * 4 + (threadIdx.x >> 6);
    if (row >= 2 * N) return;
    int lane = threadIdx.x & 63;
    int q = lane >> 4;          // quarter 0..3
    int l16 = lane & 15;
    size_t NC = (size_t)N * CCH;

    const __half* hcL;
    const int* sdL;
    int beg, end;
    float ddL;
    float4 bias;
    float* op;
    float4 acc = make_float4(0.f, 0.f, 0.f, 0.f);
    if (row < N) {                          // star: q0,q1=conv0; q2,q3=conv1
        int cv = q >> 1;
        const int* rsA = rs + cv * (N + 1);
        int bg = rsA[row], eg = rsA[row + 1];
        int mid = (bg + eg) >> 1;
        beg = (q & 1) ? mid : bg;
        end = (q & 1) ? eg : mid;
        hcL = h16 + (size_t)cv * NC;
        sdL = sdat + (size_t)cv * E;
        ddL = dinv[cv * N + row];
        if (!(q & 1)) acc = gat4p(hcL + (size_t)row * CCH, l16); // self-loop
        float4 bv0 = ((const float4*)b0)[l16];
        float4 bv1 = ((const float4*)b1)[l16];
        bias = make_float4(bv0.x + bv1.x, bv0.y + bv1.y,
                           bv0.z + bv1.z, bv0.w + bv1.w);
        op = out + (size_t)row * CCH;
    } else {                                // gal: 4 segments of one list
        int r = row - N;
        const int* rs2 = rs + 2 * (N + 1);
        int bg = rs2[r], eg = rs2[r + 1];
        int len = eg - bg;
        beg = bg + ((len * q) >> 2);
        end = bg + ((len * (q + 1)) >> 2);
        hcL = h16 + 2 * NC;
        sdL = sdat + 2 * (size_t)E;
        ddL = dinv[2 * N + r];
        if (q == 0) acc = gat4p(hcL + (size_t)r * CCH, l16);
        bias = ((const float4*)b2)[l16];
        op = out + NC + (size_t)r * CCH;
    }

    int i = beg;
    for (; i + 7 < end; i += 8) {           // unpredicated steady state
        int4a q0 = *(const int4a*)(sdL + i);
        int4a q1 = *(const int4a*)(sdL + i + 4);
        float4 v0 = gat4p(hcL + (size_t)q0.x * CCH, l16);
        float4 v1 = gat4p(hcL + (size_t)q0.y * CCH, l16);
        float4 v2 = gat4p(hcL + (size_t)q0.z * CCH, l16);
        float4 v3 = gat4p(hcL + (size_t)q0.w * CCH, l16);
        float4 v4 = gat4p(hcL + (size_t)q1.x * CCH, l16);
        float4 v5 = gat4p(hcL + (size_t)q1.y * CCH, l16);
        float4 v6 = gat4p(hcL + (size_t)q1.z * CCH, l16);
        float4 v7 = gat4p(hcL + (size_t)q1.w * CCH, l16);
        acc4(acc, v0); acc4(acc, v1); acc4(acc, v2); acc4(acc, v3);
        acc4(acc, v4); acc4(acc, v5); acc4(acc, v6); acc4(acc, v7);
    }
    if (i < end) {                          // ONE masked 8-wide tail shot
        // index over-read stays inside workspace (sdat is followed by H).
        int4a q0 = *(const int4a*)(sdL + i);
        int4a q1 = *(const int4a*)(sdL + i + 4);
        const __half* p0 = hcL + (size_t)q0.x * CCH;   // i < end: valid
        const __half* p1 = (i + 1 < end) ? hcL + (size_t)q0.y * CCH : zrow;
        const __half* p2 = (i + 2 < end) ? hcL + (size_t)q0.z * CCH : zrow;
        const __half* p3 = (i + 3 < end) ? hcL + (size_t)q0.w * CCH : zrow;
        const __half* p4 = (i + 4 < end) ? hcL + (size_t)q1.x * CCH : zrow;
        const __half* p5 = (i + 5 < end) ? hcL + (size_t)q1.y * CCH : zrow;
        const __half* p6 = (i + 6 < end) ? hcL + (size_t)q1.z * CCH : zrow;
        const __half* p7 = (i + 7 < end) ? hcL + (size_t)q1.w * CCH : zrow;
        float4 v0 = gat4p(p0, l16);
        float4 v1 = gat4p(p1, l16);
        float4 v2 = gat4p(p2, l16);
        float4 v3 = gat4p(p3, l16);
        float4 v4 = gat4p(p4, l16);
        float4 v5 = gat4p(p5, l16);
        float4 v6 = gat4p(p6, l16);
        float4 v7 = gat4p(p7, l16);
        acc4(acc, v0); acc4(acc, v1); acc4(acc, v2); acc4(acc, v3);
        acc4(acc, v4); acc4(acc, v5); acc4(acc, v6); acc4(acc, v7);
    }

    float4 t;
    t.x = acc.x * ddL; t.y = acc.y * ddL; t.z = acc.z * ddL; t.w = acc.w * ddL;
    t.x += __shfl_xor(t.x, 16, 64); t.y += __shfl_xor(t.y, 16, 64);
    t.z += __shfl_xor(t.z, 16, 64); t.w += __shfl_xor(t.w, 16, 64);
    t.x += __shfl_xor(t.x, 32, 64); t.y += __shfl_xor(t.y, 32, 64);
    t.z += __shfl_xor(t.z, 32, 64); t.w += __shfl_xor(t.w, 32, 64);
    if (lane < 16) {
        t.x += bias.x; t.y += bias.y; t.z += bias.z; t.w += bias.w;
        ((float4*)op)[l16] = t;
    }
}

static inline size_t align256(size_t x) { return (x + 255) & ~(size_t)255; }

extern "C" void kernel_launch(void* const* d_in, const int* in_sizes, int n_in,
                              void* d_out, int out_size, void* d_ws, size_t ws_size,
                              hipStream_t stream) {
    const float* x_star = (const float*)d_in[0];
    const float* x_gal  = (const float*)d_in[1];
    const int*   e_ssn  = (const int*)d_in[2];
    const int*   e_ssf  = (const int*)d_in[3];
    const int*   e_ggn  = (const int*)d_in[4];
    const float* W_ssn  = (const float*)d_in[5];
    const float* W_ssf  = (const float*)d_in[6];
    const float* W_ggn  = (const float*)d_in[7];
    const float* b_ssn  = (const float*)d_in[8];
    const float* b_ssf  = (const float*)d_in[9];
    const float* b_ggn  = (const float*)d_in[10];

    const int N  = in_sizes[0] / CCH;       // 50000 (src+dst fit 16-bit pack)
    const int E  = in_sizes[2] / 2;         // 1000000
    const size_t NC = (size_t)N * CCH;
    const int NB   = (N + RPB - 1) / RPB;   // 1563 buckets per conv
    const int NBLK = (E + PCH - 1) / PCH;   // 123 partition blocks per conv

    // workspace layout
    char* w = (char*)d_ws;
    __half*   h16    = (__half*)w;   w += align256((size_t)3 * NC * 2);
    float*    dinv   = (float*)w;    w += align256((size_t)3 * N * 4);
    unsigned* bdata  = (unsigned*)w; w += align256((size_t)3 * E * 4);
    int*      sdat   = (int*)w;      w += align256((size_t)3 * E * 4);
    int*      H      = (int*)w;      w += align256((size_t)3 * NBLK * NB * 4);
    int*      bstart = (int*)w;      w += align256((size_t)3 * (NB + 1) * 4);
    int*      rs     = (int*)w;      w += align256((size_t)3 * (N + 1) * 4);
    __half*   zrow   = (__half*)w;   w += align256((size_t)CCH * 2);

    const int B = 256;

    k_hist<<<dim3(NBLK, 3), B, 0, stream>>>(e_ssn, e_ssf, e_ggn, H, E, NB, NBLK);
    k_bscan<<<3, 1024, 0, stream>>>(H, bstart, zrow, NB, E, NBLK);
    k_colscan<<<dim3((NB + 3) / 4, 3), B, 0, stream>>>(H, bstart, NB, NBLK);
    k_part2<<<dim3(NBLK, 3), B, 0, stream>>>(e_ssn, e_ssf, e_ggn, H, bstart,
                                             bdata, E, NB, NBLK);
    k_sort32<<<dim3((NB + SG - 1) / SG, 3), B, 0, stream>>>(bdata, bstart, sdat,
                                                            rs, dinv, E, N, NB);
    k_gemm_all<<<dim3((N + GR - 1) / GR, 3), B, 0, stream>>>(x_star, x_gal,
                                                             W_ssn, W_ssf, W_ggn,
                                                             dinv, h16, N);
    k_pull<<<(2 * N + 3) / 4, B, 0, stream>>>(rs, sdat, h16, dinv, zrow,
                                              b_ssn, b_ssf, b_ggn,
                                              (float*)d_out, N, E);
}

// Round 5
// 232.853 us; speedup vs baseline: 1.2036x; 1.2036x over previous
//
#include <hip/hip_runtime.h>
#include <hip/hip_fp16.h>

#define CCH 64      // channels
#define RPB 32      // rows per bucket
#define PCH 8192    // edges per partition block
#define NBMAX 1568  // >= NB = ceil(50000/32) = 1563
#define GR 64       // rows per gemm block
#define SG 8        // buckets per sort block
#define STCAP 8192  // sort32 LDS staging capacity (recs)

typedef int int4a __attribute__((ext_vector_type(4), aligned(4)));

// ---- pass A: per-block bucket histogram -> H[c][blk][b]; also cnt totals
//      (R0 scheme: global-atomic cnt accumulation measured cheap; the 3-block
//      H-column-sum replacement in R3 cost ~44 us — reverted). ----
__global__ void __launch_bounds__(256) k_hist(const int* __restrict__ e0,
        const int* __restrict__ e1, const int* __restrict__ e2,
        int* __restrict__ H, int* __restrict__ cnt, int E, int NB, int NBLK) {
    int c = blockIdx.y;
    const int* dd = ((c == 0) ? e0 : (c == 1) ? e1 : e2) + E;
    int base = blockIdx.x * PCH;
    int nE = E - base; if (nE > PCH) nE = PCH;
    __shared__ int hist[NBMAX];
    int t = threadIdx.x;
    for (int i = t; i < NB; i += 256) hist[i] = 0;
    __syncthreads();
    for (int k = t * 4; k < nE; k += 1024) {
        if (k + 3 < nE) {
            int4a d = *(const int4a*)(dd + base + k);
            atomicAdd(&hist[d.x >> 5], 1); atomicAdd(&hist[d.y >> 5], 1);
            atomicAdd(&hist[d.z >> 5], 1); atomicAdd(&hist[d.w >> 5], 1);
        } else {
            for (int j = k; j < nE; ++j) atomicAdd(&hist[dd[base + j] >> 5], 1);
        }
    }
    __syncthreads();
    int* Hrow = H + ((size_t)c * NBLK + blockIdx.x) * NB;
    for (int i = t; i < NB; i += 256) {
        int h = hist[i];
        Hrow[i] = h;
        if (h) atomicAdd(&cnt[c * NB + i], h);
    }
}

// ---- exclusive scan of NB bucket totals per conv -> bstart; zeroes zrow ----
__global__ void __launch_bounds__(1024) k_bscan(const int* __restrict__ cnt,
        int* __restrict__ bstart, __half* __restrict__ zrow, int NB, int E) {
    int c = blockIdx.x, t = threadIdx.x;
    if (c == 0 && t < 32) ((float*)zrow)[t] = 0.f;
    __shared__ int sm[1024];
    int i0 = 2 * t, i1 = 2 * t + 1;
    int v0 = (i0 < NB) ? cnt[c * NB + i0] : 0;
    int v1 = (i1 < NB) ? cnt[c * NB + i1] : 0;
    sm[t] = v0 + v1;
    __syncthreads();
    #pragma unroll
    for (int off = 1; off < 1024; off <<= 1) {
        int u = (t >= off) ? sm[t - off] : 0;
        __syncthreads();
        sm[t] += u;
        __syncthreads();
    }
    int ex = sm[t] - (v0 + v1);
    if (i0 < NB) bstart[c * (NB + 1) + i0] = ex;
    if (i1 < NB) bstart[c * (NB + 1) + i1] = ex + v0;
    if (t == 0) bstart[c * (NB + 1) + NB] = E;
}

// ---- pass B: per-bucket scan over blocks: H <- bstart + prefix ----
__global__ void __launch_bounds__(256) k_colscan(int* __restrict__ H,
        const int* __restrict__ bstart, int NB, int NBLK) {
    int c = blockIdx.y;
    int b = blockIdx.x * 4 + (threadIdx.x >> 6);
    if (b >= NB) return;
    int l = threadIdx.x & 63;
    int* Hc = H + (size_t)c * NBLK * NB;
    int run = bstart[c * (NB + 1) + b];
    for (int c0 = 0; c0 < NBLK; c0 += 64) {
        int blk = c0 + l;
        int v = (blk < NBLK) ? Hc[(size_t)blk * NB + b] : 0;
        int s = v;
        #pragma unroll
        for (int off = 1; off < 64; off <<= 1) {
            int u = __shfl_up(s, off, 64);
            if (l >= off) s += u;
        }
        if (blk < NBLK) Hc[(size_t)blk * NB + b] = run + s - v;
        run += __shfl(s, 63, 64);
    }
}

// ---- pass C: LDS-STAGED partition. Local counts via the H-diff identity
//      h_local[blk][b] = H[blk+1][b] - H[blk][b] (bstart[b+1] for last block):
//      no edge re-read, no histogram atomics (verified R1-R3). ----
__global__ void __launch_bounds__(256) k_part2(const int* __restrict__ e0,
        const int* __restrict__ e1, const int* __restrict__ e2,
        const int* __restrict__ H, const int* __restrict__ bstart,
        unsigned* __restrict__ bdata, int E, int NB, int NBLK) {
    int c = blockIdx.y;
    const int* ed = (c == 0) ? e0 : (c == 1) ? e1 : e2;
    int base = blockIdx.x * PCH;
    int nE = E - base; if (nE > PCH) nE = PCH;
    __shared__ unsigned staged[PCH];    // 32 KB
    __shared__ int hist[NBMAX];
    __shared__ int off[NBMAX];
    __shared__ int sm[256];
    int t = threadIdx.x;
    const int* Hcur = H + ((size_t)c * NBLK + blockIdx.x) * NB;
    const int* Hnxt = (blockIdx.x == NBLK - 1) ? (bstart + c * (NB + 1) + 1)
                                               : (Hcur + NB);
    for (int i = t; i < NB; i += 256) {
        int cu = Hcur[i];
        off[i] = cu;
        hist[i] = Hnxt[i] - cu;         // this block's local count for bucket i
    }
    __syncthreads();
    int C = (NB + 255) >> 8;
    int lo = t * C, hi = lo + C; if (hi > NB) hi = NB; if (lo > NB) lo = NB;
    int s = 0;
    for (int i = lo; i < hi; ++i) s += hist[i];
    sm[t] = s;
    __syncthreads();
    #pragma unroll
    for (int o = 1; o < 256; o <<= 1) {
        int u = (t >= o) ? sm[t - o] : 0;
        __syncthreads();
        sm[t] += u;
        __syncthreads();
    }
    int run = (t == 0) ? 0 : sm[t - 1];
    for (int i = lo; i < hi; ++i) {
        int h = hist[i];
        off[i] -= run;      // global offset minus staging start
        hist[i] = run;      // staging cursor
        run += h;
    }
    __syncthreads();
    for (int k = t * 4; k < nE; k += 1024) {
        if (k + 3 < nE) {
            int4a s4 = *(const int4a*)(ed + base + k);
            int4a d4 = *(const int4a*)(ed + E + base + k);
            int sl;
            sl = atomicAdd(&hist[d4.x >> 5], 1); staged[sl] = (unsigned)s4.x | ((unsigned)d4.x << 16);
            sl = atomicAdd(&hist[d4.y >> 5], 1); staged[sl] = (unsigned)s4.y | ((unsigned)d4.y << 16);
            sl = atomicAdd(&hist[d4.z >> 5], 1); staged[sl] = (unsigned)s4.z | ((unsigned)d4.z << 16);
            sl = atomicAdd(&hist[d4.w >> 5], 1); staged[sl] = (unsigned)s4.w | ((unsigned)d4.w << 16);
        } else {
            for (int j = k; j < nE; ++j) {
                int s0 = ed[base + j];
                int d0 = ed[E + base + j];
                int sl = atomicAdd(&hist[d0 >> 5], 1);
                staged[sl] = (unsigned)s0 | ((unsigned)d0 << 16);
            }
        }
    }
    __syncthreads();
    unsigned* bo = bdata + (size_t)c * E;
    for (int sI = t; sI < nE; sI += 256) {
        unsigned rec = staged[sI];
        int b = (int)(rec >> 16) >> 5;
        bo[off[b] + sI] = rec;
    }
}

// ---- within-bucket 32-way counting sort, SG buckets per block,
//      SINGLE global read: recs staged in LDS (fallback if region > STCAP) ----
__global__ void __launch_bounds__(256) k_sort32(const unsigned* __restrict__ bdata,
        const int* __restrict__ bstart, int* __restrict__ sdat,
        int* __restrict__ rs, float* __restrict__ dinv, int E, int N, int NB) {
    int c = blockIdx.y;
    int b0 = blockIdx.x * SG;
    __shared__ unsigned staged[STCAP];  // 32 KB
    __shared__ int cnt[SG * RPB];
    __shared__ int cur[SG * RPB];
    __shared__ int sb[SG + 1];
    int t = threadIdx.x;
    cnt[t] = 0;
    if (t <= SG) {
        int b = b0 + t; if (b > NB) b = NB;
        sb[t] = bstart[c * (NB + 1) + b];
    }
    __syncthreads();
    int s0 = sb[0], sE = sb[SG];
    int n = sE - s0;
    const unsigned* bd = bdata + (size_t)c * E;
    bool fits = (n <= STCAP);
    if (fits) {
        for (int i = t; i < n; i += 256) staged[i] = bd[s0 + i];
        __syncthreads();
        for (int i = t; i < n; i += 256) {
            int dst = (int)(staged[i] >> 16);
            atomicAdd(&cnt[((dst >> 5) - b0) * RPB + (dst & 31)], 1);
        }
    } else {
        for (int i = s0 + t; i < sE; i += 256) {
            int dst = (int)(bd[i] >> 16);
            atomicAdd(&cnt[((dst >> 5) - b0) * RPB + (dst & 31)], 1);
        }
    }
    __syncthreads();
    {
        int v = cnt[t];
        int s = v;
        #pragma unroll
        for (int off = 1; off < RPB; off <<= 1) {
            int u = __shfl_up(s, off, RPB);
            if ((t & (RPB - 1)) >= off) s += u;
        }
        int g = t >> 5, r = t & 31;
        int ex = sb[g] + s - v;
        cur[t] = ex;
        int row = (b0 + g) * RPB + r;
        if (b0 + g < NB && row < N) {
            rs[c * (N + 1) + row] = ex;
            dinv[c * N + row] = rsqrtf((float)(v + 1));
        }
    }
    if (blockIdx.x == 0 && t == 0) rs[c * (N + 1) + N] = E;
    __syncthreads();
    int* so = sdat + (size_t)c * E;
    if (fits) {
        for (int i = t; i < n; i += 256) {
            unsigned r = staged[i];
            int dst = (int)(r >> 16);
            int slot = atomicAdd(&cur[((dst >> 5) - b0) * RPB + (dst & 31)], 1);
            so[slot] = (int)(r & 0xFFFFu);
        }
    } else {
        for (int i = s0 + t; i < sE; i += 256) {
            unsigned r = bd[i];
            int dst = (int)(r >> 16);
            int slot = atomicAdd(&cur[((dst >> 5) - b0) * RPB + (dst & 31)], 1);
            so[slot] = (int)(r & 0xFFFFu);
        }
    }
}

// ---- h16[c,row,:] = fp16( (x_row . W_c) * dinv[c,row] ), register-tiled.
//      Star path computes BOTH conv0 and conv1 from ONE x_star read
//      (saves a 12.8 MB pass + one xT staging). Gal path unchanged. ----
__global__ void __launch_bounds__(256) k_gemm_all(const float* __restrict__ xs_,
        const float* __restrict__ xg_, const float* __restrict__ W0,
        const float* __restrict__ W1, const float* __restrict__ W2,
        const float* __restrict__ dinv, __half* __restrict__ h16, int N) {
    int star = (blockIdx.y == 0);
    const float* x = star ? xs_ : xg_;
    __shared__ float Ws[2][CCH * CCH];    // 32 KB (gal uses [0] only)
    __shared__ float xT[CCH * (GR + 1)];  // [k][row], stride 65
    int t = threadIdx.x;
    int row0 = blockIdx.x * GR;
    size_t NC = (size_t)N * CCH;
    if (star) {
        #pragma unroll
        for (int j = 0; j < 4; ++j) {
            int idx = j * 1024 + t * 4;
            *(float4*)(&Ws[0][idx]) = *(const float4*)(W0 + idx);
            *(float4*)(&Ws[1][idx]) = *(const float4*)(W1 + idx);
        }
    } else {
        #pragma unroll
        for (int j = 0; j < 4; ++j) {
            int idx = j * 1024 + t * 4;
            *(float4*)(&Ws[0][idx]) = *(const float4*)(W2 + idx);
        }
    }
    #pragma unroll
    for (int j = 0; j < 4; ++j) {
        int idx = t + j * 256;
        int r = idx >> 4;
        int c0 = (idx & 15) * 4;
        int row = row0 + r;
        float4 v = make_float4(0.f, 0.f, 0.f, 0.f);
        if (row < N) v = *(const float4*)(x + (size_t)row * CCH + c0);
        xT[(c0 + 0) * (GR + 1) + r] = v.x;
        xT[(c0 + 1) * (GR + 1) + r] = v.y;
        xT[(c0 + 2) * (GR + 1) + r] = v.z;
        xT[(c0 + 3) * (GR + 1) + r] = v.w;
    }
    __syncthreads();
    int c4 = (t & 15) * 4;
    int r0 = (t >> 4) * 4;
    if (star) {
        float4 a0 = make_float4(0.f, 0.f, 0.f, 0.f), a1 = a0, a2 = a0, a3 = a0;
        float4 d0 = a0, d1 = a0, d2 = a0, d3 = a0;
        #pragma unroll 4
        for (int k = 0; k < CCH; ++k) {
            float4 wv = *(float4*)(&Ws[0][k * CCH + c4]);
            float4 uv = *(float4*)(&Ws[1][k * CCH + c4]);
            float x0 = xT[k * (GR + 1) + r0 + 0];
            float x1 = xT[k * (GR + 1) + r0 + 1];
            float x2 = xT[k * (GR + 1) + r0 + 2];
            float x3 = xT[k * (GR + 1) + r0 + 3];
            a0.x += x0 * wv.x; a0.y += x0 * wv.y; a0.z += x0 * wv.z; a0.w += x0 * wv.w;
            a1.x += x1 * wv.x; a1.y += x1 * wv.y; a1.z += x1 * wv.z; a1.w += x1 * wv.w;
            a2.x += x2 * wv.x; a2.y += x2 * wv.y; a2.z += x2 * wv.z; a2.w += x2 * wv.w;
            a3.x += x3 * wv.x; a3.y += x3 * wv.y; a3.z += x3 * wv.z; a3.w += x3 * wv.w;
            d0.x += x0 * uv.x; d0.y += x0 * uv.y; d0.z += x0 * uv.z; d0.w += x0 * uv.w;
            d1.x += x1 * uv.x; d1.y += x1 * uv.y; d1.z += x1 * uv.z; d1.w += x1 * uv.w;
            d2.x += x2 * uv.x; d2.y += x2 * uv.y; d2.z += x2 * uv.z; d2.w += x2 * uv.w;
            d3.x += x3 * uv.x; d3.y += x3 * uv.y; d3.z += x3 * uv.z; d3.w += x3 * uv.w;
        }
        float4 av[4] = {a0, a1, a2, a3};
        float4 dv4[4] = {d0, d1, d2, d3};
        #pragma unroll
        for (int i = 0; i < 4; ++i) {
            int row = row0 + r0 + i;
            if (row < N) {
                float dd0 = dinv[row];
                float dd1 = dinv[N + row];
                union { __half2 h2[2]; float2 f2; } u;
                u.h2[0] = __floats2half2_rn(av[i].x * dd0, av[i].y * dd0);
                u.h2[1] = __floats2half2_rn(av[i].z * dd0, av[i].w * dd0);
                *(float2*)(h16 + (size_t)row * CCH + c4) = u.f2;
                u.h2[0] = __floats2half2_rn(dv4[i].x * dd1, dv4[i].y * dd1);
                u.h2[1] = __floats2half2_rn(dv4[i].z * dd1, dv4[i].w * dd1);
                *(float2*)(h16 + NC + (size_t)row * CCH + c4) = u.f2;
            }
        }
    } else {
        float4 a0 = make_float4(0.f, 0.f, 0.f, 0.f), a1 = a0, a2 = a0, a3 = a0;
        #pragma unroll 8
        for (int k = 0; k < CCH; ++k) {
            float4 wv = *(float4*)(&Ws[0][k * CCH + c4]);
            float x0 = xT[k * (GR + 1) + r0 + 0];
            float x1 = xT[k * (GR + 1) + r0 + 1];
            float x2 = xT[k * (GR + 1) + r0 + 2];
            float x3 = xT[k * (GR + 1) + r0 + 3];
            a0.x += x0 * wv.x; a0.y += x0 * wv.y; a0.z += x0 * wv.z; a0.w += x0 * wv.w;
            a1.x += x1 * wv.x; a1.y += x1 * wv.y; a1.z += x1 * wv.z; a1.w += x1 * wv.w;
            a2.x += x2 * wv.x; a2.y += x2 * wv.y; a2.z += x2 * wv.z; a2.w += x2 * wv.w;
            a3.x += x3 * wv.x; a3.y += x3 * wv.y; a3.z += x3 * wv.z; a3.w += x3 * wv.w;
        }
        float4 av[4] = {a0, a1, a2, a3};
        #pragma unroll
        for (int i = 0; i < 4; ++i) {
            int row = row0 + r0 + i;
            if (row < N) {
                float dd = dinv[2 * N + row];
                union { __half2 h2[2]; float2 f2; } u;
                u.h2[0] = __floats2half2_rn(av[i].x * dd, av[i].y * dd);
                u.h2[1] = __floats2half2_rn(av[i].z * dd, av[i].w * dd);
                *(float2*)(h16 + 2 * NC + (size_t)row * CCH + c4) = u.f2;
            }
        }
    }
}

// ---- gather 4 fp16 channels (8B dwordx2) from a row pointer ----
__device__ __forceinline__ float4 gat4p(const __half* __restrict__ p, int l16) {
    union { float2 f2; __half2 h2[2]; } u;
    u.f2 = ((const float2*)p)[l16];
    float2 a = __half22float2(u.h2[0]);
    float2 b = __half22float2(u.h2[1]);
    return make_float4(a.x, a.y, b.x, b.y);
}

__device__ __forceinline__ void acc4(float4& a, float4 v) {
    a.x += v.x; a.y += v.y; a.z += v.z; a.w += v.w;
}

// ---- fused pull: wave per row; four quarter-waves (16 lanes x 4ch) walk
//      4 list segments. Unpredicated 8-wide steady state + ONE masked
//      8-wide tail via L1-hot zero row (R3-measured 67.0 us). ----
__global__ void __launch_bounds__(256) k_pull(const int* __restrict__ rs,
        const int* __restrict__ sdat, const __half* __restrict__ h16,
        const float* __restrict__ dinv, const __half* __restrict__ zrow,
        const float* __restrict__ b0, const float* __restrict__ b1,
        const float* __restrict__ b2,
        float* __restrict__ out, int N, int E) {
    int row = blockIdx.x * 4 + (threadIdx.x >> 6);
    if (row >= 2 * N) return;
    int lane = threadIdx.x & 63;
    int q = lane >> 4;          // quarter 0..3
    int l16 = lane & 15;
    size_t NC = (size_t)N * CCH;

    const __half* hcL;
    const int* sdL;
    int beg, end;
    float ddL;
    float4 bias;
    float* op;
    float4 acc = make_float4(0.f, 0.f, 0.f, 0.f);
    if (row < N) {                          // star: q0,q1=conv0; q2,q3=conv1
        int cv = q >> 1;
        const int* rsA = rs + cv * (N + 1);
        int bg = rsA[row], eg = rsA[row + 1];
        int mid = (bg + eg) >> 1;
        beg = (q & 1) ? mid : bg;
        end = (q & 1) ? eg : mid;
        hcL = h16 + (size_t)cv * NC;
        sdL = sdat + (size_t)cv * E;
        ddL = dinv[cv * N + row];
        if (!(q & 1)) acc = gat4p(hcL + (size_t)row * CCH, l16); // self-loop
        float4 bv0 = ((const float4*)b0)[l16];
        float4 bv1 = ((const float4*)b1)[l16];
        bias = make_float4(bv0.x + bv1.x, bv0.y + bv1.y,
                           bv0.z + bv1.z, bv0.w + bv1.w);
        op = out + (size_t)row * CCH;
    } else {                                // gal: 4 segments of one list
        int r = row - N;
        const int* rs2 = rs + 2 * (N + 1);
        int bg = rs2[r], eg = rs2[r + 1];
        int len = eg - bg;
        beg = bg + ((len * q) >> 2);
        end = bg + ((len * (q + 1)) >> 2);
        hcL = h16 + 2 * NC;
        sdL = sdat + 2 * (size_t)E;
        ddL = dinv[2 * N + r];
        if (q == 0) acc = gat4p(hcL + (size_t)r * CCH, l16);
        bias = ((const float4*)b2)[l16];
        op = out + NC + (size_t)r * CCH;
    }

    int i = beg;
    for (; i + 7 < end; i += 8) {           // unpredicated steady state
        int4a q0 = *(const int4a*)(sdL + i);
        int4a q1 = *(const int4a*)(sdL + i + 4);
        float4 v0 = gat4p(hcL + (size_t)q0.x * CCH, l16);
        float4 v1 = gat4p(hcL + (size_t)q0.y * CCH, l16);
        float4 v2 = gat4p(hcL + (size_t)q0.z * CCH, l16);
        float4 v3 = gat4p(hcL + (size_t)q0.w * CCH, l16);
        float4 v4 = gat4p(hcL + (size_t)q1.x * CCH, l16);
        float4 v5 = gat4p(hcL + (size_t)q1.y * CCH, l16);
        float4 v6 = gat4p(hcL + (size_t)q1.z * CCH, l16);
        float4 v7 = gat4p(hcL + (size_t)q1.w * CCH, l16);
        acc4(acc, v0); acc4(acc, v1); acc4(acc, v2); acc4(acc, v3);
        acc4(acc, v4); acc4(acc, v5); acc4(acc, v6); acc4(acc, v7);
    }
    if (i < end) {                          // ONE masked 8-wide tail shot
        // index over-read stays inside workspace (sdat is followed by H).
        int4a q0 = *(const int4a*)(sdL + i);
        int4a q1 = *(const int4a*)(sdL + i + 4);
        const __half* p0 = hcL + (size_t)q0.x * CCH;   // i < end: valid
        const __half* p1 = (i + 1 < end) ? hcL + (size_t)q0.y * CCH : zrow;
        const __half* p2 = (i + 2 < end) ? hcL + (size_t)q0.z * CCH : zrow;
        const __half* p3 = (i + 3 < end) ? hcL + (size_t)q0.w * CCH : zrow;
        const __half* p4 = (i + 4 < end) ? hcL + (size_t)q1.x * CCH : zrow;
        const __half* p5 = (i + 5 < end) ? hcL + (size_t)q1.y * CCH : zrow;
        const __half* p6 = (i + 6 < end) ? hcL + (size_t)q1.z * CCH : zrow;
        const __half* p7 = (i + 7 < end) ? hcL + (size_t)q1.w * CCH : zrow;
        float4 v0 = gat4p(p0, l16);
        float4 v1 = gat4p(p1, l16);
        float4 v2 = gat4p(p2, l16);
        float4 v3 = gat4p(p3, l16);
        float4 v4 = gat4p(p4, l16);
        float4 v5 = gat4p(p5, l16);
        float4 v6 = gat4p(p6, l16);
        float4 v7 = gat4p(p7, l16);
        acc4(acc, v0); acc4(acc, v1); acc4(acc, v2); acc4(acc, v3);
        acc4(acc, v4); acc4(acc, v5); acc4(acc, v6); acc4(acc, v7);
    }

    float4 t;
    t.x = acc.x * ddL; t.y = acc.y * ddL; t.z = acc.z * ddL; t.w = acc.w * ddL;
    t.x += __shfl_xor(t.x, 16, 64); t.y += __shfl_xor(t.y, 16, 64);
    t.z += __shfl_xor(t.z, 16, 64); t.w += __shfl_xor(t.w, 16, 64);
    t.x += __shfl_xor(t.x, 32, 64); t.y += __shfl_xor(t.y, 32, 64);
    t.z += __shfl_xor(t.z, 32, 64); t.w += __shfl_xor(t.w, 32, 64);
    if (lane < 16) {
        t.x += bias.x; t.y += bias.y; t.z += bias.z; t.w += bias.w;
        ((float4*)op)[l16] = t;
    }
}

static inline size_t align256(size_t x) { return (x + 255) & ~(size_t)255; }

extern "C" void kernel_launch(void* const* d_in, const int* in_sizes, int n_in,
                              void* d_out, int out_size, void* d_ws, size_t ws_size,
                              hipStream_t stream) {
    const float* x_star = (const float*)d_in[0];
    const float* x_gal  = (const float*)d_in[1];
    const int*   e_ssn  = (const int*)d_in[2];
    const int*   e_ssf  = (const int*)d_in[3];
    const int*   e_ggn  = (const int*)d_in[4];
    const float* W_ssn  = (const float*)d_in[5];
    const float* W_ssf  = (const float*)d_in[6];
    const float* W_ggn  = (const float*)d_in[7];
    const float* b_ssn  = (const float*)d_in[8];
    const float* b_ssf  = (const float*)d_in[9];
    const float* b_ggn  = (const float*)d_in[10];

    const int N  = in_sizes[0] / CCH;       // 50000 (src+dst fit 16-bit pack)
    const int E  = in_sizes[2] / 2;         // 1000000
    const size_t NC = (size_t)N * CCH;
    const int NB   = (N + RPB - 1) / RPB;   // 1563 buckets per conv
    const int NBLK = (E + PCH - 1) / PCH;   // 123 partition blocks per conv

    // workspace layout
    char* w = (char*)d_ws;
    __half*   h16    = (__half*)w;   w += align256((size_t)3 * NC * 2);
    float*    dinv   = (float*)w;    w += align256((size_t)3 * N * 4);
    unsigned* bdata  = (unsigned*)w; w += align256((size_t)3 * E * 4);
    int*      sdat   = (int*)w;      w += align256((size_t)3 * E * 4);
    int*      H      = (int*)w;      w += align256((size_t)3 * NBLK * NB * 4);
    int*      cnt    = (int*)w;      w += align256((size_t)3 * NB * 4);
    int*      bstart = (int*)w;      w += align256((size_t)3 * (NB + 1) * 4);
    int*      rs     = (int*)w;      w += align256((size_t)3 * (N + 1) * 4);
    __half*   zrow   = (__half*)w;   w += align256((size_t)CCH * 2);

    const int B = 256;

    hipMemsetAsync(cnt, 0, (size_t)3 * NB * 4, stream);
    k_hist<<<dim3(NBLK, 3), B, 0, stream>>>(e_ssn, e_ssf, e_ggn, H, cnt, E, NB, NBLK);
    k_bscan<<<3, 1024, 0, stream>>>(cnt, bstart, zrow, NB, E);
    k_colscan<<<dim3((NB + 3) / 4, 3), B, 0, stream>>>(H, bstart, NB, NBLK);
    k_part2<<<dim3(NBLK, 3), B, 0, stream>>>(e_ssn, e_ssf, e_ggn, H, bstart,
                                             bdata, E, NB, NBLK);
    k_sort32<<<dim3((NB + SG - 1) / SG, 3), B, 0, stream>>>(bdata, bstart, sdat,
                                                            rs, dinv, E, N, NB);
    k_gemm_all<<<dim3((N + GR - 1) / GR, 2), B, 0, stream>>>(x_star, x_gal,
                                                             W_ssn, W_ssf, W_ggn,
                                                             dinv, h16, N);
    k_pull<<<(2 * N + 3) / 4, B, 0, stream>>>(rs, sdat, h16, dinv, zrow,
                                              b_ssn, b_ssf, b_ggn,
                                              (float*)d_out, N, E);
}